// Round 4
// baseline (1458.976 us; speedup 1.0000x reference)
//
#include <hip/hip_runtime.h>
#include <cstddef>

#define Bb 16
#define Ll 1024
#define OBS 64
#define Hh 256
#define NBLK 4
#define NST 16
#define DCV 4
#define DIN 512
#define DTR 16
#define NC 32            // chunks over L
#define CL (Ll / NC)     // 32 steps per chunk

typedef short short8 __attribute__((ext_vector_type(8)));
typedef float f32x4 __attribute__((ext_vector_type(4)));

// ---------------- workspace layout (floats) ----------------
static const size_t OFF_H0   = 0;
static const size_t OFF_H1   = OFF_H0 + (size_t)Bb * Ll * Hh;
static const size_t OFF_XIN  = OFF_H1 + (size_t)Bb * Ll * Hh;
static const size_t OFF_Z    = OFF_XIN + (size_t)Bb * Ll * DIN;
static const size_t OFF_U    = OFF_Z   + (size_t)Bb * Ll * DIN;
static const size_t OFF_PROJ = OFF_U   + (size_t)Bb * Ll * DIN;      // [M,48]
static const size_t OFF_HST  = OFF_PROJ + (size_t)Bb * Ll * 48;      // [B,NC,NST,DIN]
static const size_t OFF_WC   = OFF_HST + (size_t)Bb * NC * NST * DIN;
// ushort offsets inside WC region:
static const size_t WPW_HI  = 0;
static const size_t WPW_LO  = 16384;
static const size_t WIPW_HI = 32768;
static const size_t WIPW_LO = WIPW_HI + 1048576;
static const size_t WOPW_HI = WIPW_LO + 1048576;
static const size_t WOPW_LO = WOPW_HI + 524288;

__device__ inline unsigned short f32_to_bf16(float v) {
    unsigned int u = __float_as_uint(v);
    u += 0x7fffu + ((u >> 16) & 1u);
    return (unsigned short)(u >> 16);
}
__device__ inline float bf16_to_f32(unsigned short h) {
    return __uint_as_float((unsigned int)h << 16);
}
__device__ inline float softplusf(float s) {
    return fmaxf(s, 0.f) + log1pf(__expf(-fabsf(s)));
}

// ---------------- weight fp32 -> bf16 hi/lo conversion ----------------
__global__ __launch_bounds__(256) void convert_w_kernel(
    const float* __restrict__ w,
    unsigned short* __restrict__ hi,
    unsigned short* __restrict__ lo, int n4)
{
    int i = blockIdx.x * 256 + threadIdx.x;
    if (i >= n4) return;
    float4 v4 = ((const float4*)w)[i];
    float vv[4] = {v4.x, v4.y, v4.z, v4.w};
#pragma unroll
    for (int e = 0; e < 4; ++e) {
        unsigned short hb = f32_to_bf16(vv[e]);
        float res = vv[e] - bf16_to_f32(hb);
        hi[i * 4 + e] = hb;
        lo[i * 4 + e] = f32_to_bf16(res);
    }
}

// ---------------- bf16x3 MFMA GEMM: C[M,N'] = A[M,K](fp32) * W[N,K]^T ----------------
template <int BM, int WR>
__global__ __launch_bounds__(256) void gemm_mfma3(
    const float* __restrict__ A, int lda,
    const unsigned short* __restrict__ Whi,
    const unsigned short* __restrict__ Wlo,
    const float* __restrict__ bias,
    float* __restrict__ C0,
    float* __restrict__ C1,
    int N, int K, int splitN)
{
    constexpr int WC_ = 4 / WR;
    constexpr int MI = (BM / WR) / 16;
    constexpr int NJ = (128 / WC_) / 16;
    constexpr int ASLOT = BM * 4 / 256;

    __shared__ unsigned short AsH[BM * 32], AsL[BM * 32];
    __shared__ unsigned short BsH[128 * 32], BsL[128 * 32];

    const int tid  = threadIdx.x;
    const int lane = tid & 63;
    const int w    = tid >> 6;
    const int wr   = w / WC_;
    const int wc   = w % WC_;
    const int m0   = blockIdx.y * BM;
    const int n0   = blockIdx.x * 128;

    f32x4 acc[MI][NJ] = {};

    for (int k0 = 0; k0 < K; k0 += 32) {
#pragma unroll
        for (int sI = 0; sI < ASLOT; ++sI) {
            int s = tid + sI * 256;
            int row = s >> 2, kb = s & 3;
            const float* ap = A + (size_t)(m0 + row) * lda + k0 + kb * 8;
            float4 v0 = *(const float4*)ap;
            float4 v1 = *(const float4*)(ap + 4);
            float vv[8] = {v0.x, v0.y, v0.z, v0.w, v1.x, v1.y, v1.z, v1.w};
            short8 h8, l8;
#pragma unroll
            for (int e = 0; e < 8; ++e) {
                unsigned short hb = f32_to_bf16(vv[e]);
                float res = vv[e] - bf16_to_f32(hb);
                h8[e] = (short)hb;
                l8[e] = (short)f32_to_bf16(res);
            }
            *(short8*)&AsH[s * 8] = h8;
            *(short8*)&AsL[s * 8] = l8;
        }
#pragma unroll
        for (int sI = 0; sI < 2; ++sI) {
            int s = tid + sI * 256;
            int row = s >> 2, kb = s & 3;
            size_t off = (size_t)(n0 + row) * K + k0 + kb * 8;
            *(short8*)&BsH[s * 8] = *(const short8*)(Whi + off);
            *(short8*)&BsL[s * 8] = *(const short8*)(Wlo + off);
        }
        __syncthreads();

        const int rr = lane & 15;
        const int kq = lane >> 4;
        short8 ah[MI], al[MI];
#pragma unroll
        for (int i = 0; i < MI; ++i) {
            int row = wr * (BM / WR) + i * 16 + rr;
            ah[i] = *(const short8*)&AsH[row * 32 + kq * 8];
            al[i] = *(const short8*)&AsL[row * 32 + kq * 8];
        }
#pragma unroll
        for (int j = 0; j < NJ; ++j) {
            int col = wc * (128 / WC_) + j * 16 + rr;
            short8 bh = *(const short8*)&BsH[col * 32 + kq * 8];
            short8 bl = *(const short8*)&BsL[col * 32 + kq * 8];
#pragma unroll
            for (int i = 0; i < MI; ++i) {
                acc[i][j] = __builtin_amdgcn_mfma_f32_16x16x32_bf16(ah[i], bh, acc[i][j], 0, 0, 0);
                acc[i][j] = __builtin_amdgcn_mfma_f32_16x16x32_bf16(ah[i], bl, acc[i][j], 0, 0, 0);
                acc[i][j] = __builtin_amdgcn_mfma_f32_16x16x32_bf16(al[i], bh, acc[i][j], 0, 0, 0);
            }
        }
        __syncthreads();
    }

    const int rr = lane & 15;
    const int rq = lane >> 4;
#pragma unroll
    for (int i = 0; i < MI; ++i) {
#pragma unroll
        for (int j = 0; j < NJ; ++j) {
            int col = n0 + wc * (128 / WC_) + j * 16 + rr;
            float badd = bias ? bias[col] : 0.f;
#pragma unroll
            for (int r = 0; r < 4; ++r) {
                int row = m0 + wr * (BM / WR) + i * 16 + rq * 4 + r;
                float v = acc[i][j][r] + badd;
                if (col < splitN)
                    C0[(size_t)row * splitN + col] = v;
                else
                    C1[(size_t)row * (N - splitN) + (col - splitN)] = v;
            }
        }
    }
}

// ---------------- fp32 GEMM (x_proj, N=48) ----------------
template <int ACT>
__global__ __launch_bounds__(256) void gemm_nt(
    const float* __restrict__ A, int lda,
    const float* __restrict__ W,
    const float* __restrict__ bias,
    float* __restrict__ C0, float* __restrict__ C1,
    int M, int N, int K, int splitN)
{
    __shared__ float As[16][68];
    __shared__ float Ws[16][68];

    const int tid = threadIdx.x;
    const int m0 = blockIdx.y * 64;
    const int n0 = blockIdx.x * 64;
    const int tx = tid & 15;
    const int ty = tid >> 4;
    const int r  = tid >> 2;
    const int kv = (tid & 3) * 4;

    float acc[4][4] = {};

    for (int k0 = 0; k0 < K; k0 += 16) {
        float4 a4;
        {
            const float* ap = A + (size_t)(m0 + r) * lda + (k0 + kv);
            a4 = *(const float4*)ap;
        }
        float4 w4 = make_float4(0.f, 0.f, 0.f, 0.f);
        if (n0 + r < N) {
            const float* wp = W + (size_t)(n0 + r) * K + (k0 + kv);
            w4 = *(const float4*)wp;
        }
        __syncthreads();
        As[kv + 0][r] = a4.x; As[kv + 1][r] = a4.y;
        As[kv + 2][r] = a4.z; As[kv + 3][r] = a4.w;
        Ws[kv + 0][r] = w4.x; Ws[kv + 1][r] = w4.y;
        Ws[kv + 2][r] = w4.z; Ws[kv + 3][r] = w4.w;
        __syncthreads();
#pragma unroll
        for (int kk = 0; kk < 16; ++kk) {
            float4 av = *(const float4*)&As[kk][ty * 4];
            float4 wv = *(const float4*)&Ws[kk][tx * 4];
            float am[4] = {av.x, av.y, av.z, av.w};
            float wn[4] = {wv.x, wv.y, wv.z, wv.w};
#pragma unroll
            for (int i = 0; i < 4; ++i)
#pragma unroll
                for (int j = 0; j < 4; ++j)
                    acc[i][j] += am[i] * wn[j];
        }
    }

#pragma unroll
    for (int i = 0; i < 4; ++i) {
        const int row = m0 + ty * 4 + i;
#pragma unroll
        for (int j = 0; j < 4; ++j) {
            const int col = n0 + tx * 4 + j;
            if (col >= N) continue;
            float v = acc[i][j];
            if (bias) v += bias[col];
            if (ACT == 1) v = softplusf(v);
            if (col < splitN)
                C0[(size_t)row * splitN + col] = v;
            else
                C1[(size_t)row * (N - splitN) + (col - splitN)] = v;
        }
    }
}

// ---------------- causal depthwise conv1d + silu (float4 over d) ----------------
__global__ __launch_bounds__(256) void conv_silu_kernel(
    const float* __restrict__ xin,
    const float* __restrict__ cw,
    const float* __restrict__ cb,
    float* __restrict__ u, int total4)
{
    int i = blockIdx.x * 256 + threadIdx.x;
    if (i >= total4) return;
    int d4 = (i & (DIN / 4 - 1)) * 4;
    int bl = i >> 7;                 // row index in [0, B*L)
    int l  = bl & (Ll - 1);

    float4 cb4 = *(const float4*)(cb + d4);
    float acc[4] = {cb4.x, cb4.y, cb4.z, cb4.w};
    // cw rows d4..d4+3, each 4 taps
    float4 cw0 = *(const float4*)(cw + (d4 + 0) * 4);
    float4 cw1 = *(const float4*)(cw + (d4 + 1) * 4);
    float4 cw2 = *(const float4*)(cw + (d4 + 2) * 4);
    float4 cw3 = *(const float4*)(cw + (d4 + 3) * 4);
    const float* cwp[4] = {(const float*)&cw0, (const float*)&cw1,
                           (const float*)&cw2, (const float*)&cw3};
#pragma unroll
    for (int k = 0; k < DCV; ++k) {
        int ls = l - (DCV - 1) + k;
        if (ls >= 0) {
            float4 xv = *(const float4*)(xin + (size_t)(bl - (DCV - 1) + k) * DIN + d4);
            float xj[4] = {xv.x, xv.y, xv.z, xv.w};
#pragma unroll
            for (int j = 0; j < 4; ++j) acc[j] += xj[j] * cwp[j][k];
        }
    }
    float4 o;
    o.x = acc[0] / (1.f + __expf(-acc[0]));
    o.y = acc[1] / (1.f + __expf(-acc[1]));
    o.z = acc[2] / (1.f + __expf(-acc[2]));
    o.w = acc[3] / (1.f + __expf(-acc[3]));
    *(float4*)(u + (size_t)bl * DIN + d4) = o;
}

// ---------------- scan phase A: chunk-local reduce (dt fused, n split over lane pair) --
// lane pair = (b,c,d); ng = gid&1 handles states n = ng*8 .. ng*8+7.
__global__ __launch_bounds__(256) void scan_chunk_reduce(
    const float* __restrict__ u,
    const float* __restrict__ proj,   // [B*L,48]: 0..15 dtl, 16..31 Bc, 32..47 Cc
    const float* __restrict__ dpw,    // [DIN, DTR]
    const float* __restrict__ dpb,    // [DIN]
    const float* __restrict__ Alog,   // [DIN, NST]
    float* __restrict__ P,
    float* __restrict__ F)
{
    int gid = blockIdx.x * 256 + threadIdx.x;
    int ng = gid & 1;
    int d  = (gid >> 1) & (DIN - 1);
    int c  = (gid >> 10) & (NC - 1);
    int b  = gid >> 15;
    const int nb = ng * 8;

    float A[8];
#pragma unroll
    for (int j = 0; j < 8; ++j) A[j] = -__expf(Alog[d * NST + nb + j]);

    float wdt[16];
#pragma unroll
    for (int r4 = 0; r4 < 4; ++r4) {
        float4 v = *(const float4*)(dpw + d * DTR + r4 * 4);
        wdt[r4 * 4 + 0] = v.x; wdt[r4 * 4 + 1] = v.y;
        wdt[r4 * 4 + 2] = v.z; wdt[r4 * 4 + 3] = v.w;
    }
    const float bdt = dpb[d];

    float h[8], p[8];
#pragma unroll
    for (int j = 0; j < 8; ++j) { h[j] = 0.f; p[j] = 1.f; }

    const int l0 = c * CL;
    for (int l = l0; l < l0 + CL; ++l) {
        size_t row = (size_t)b * Ll + l;
        const float* pr = proj + row * 48;
        float4 t0 = *(const float4*)(pr + 0);
        float4 t1 = *(const float4*)(pr + 4);
        float4 t2 = *(const float4*)(pr + 8);
        float4 t3 = *(const float4*)(pr + 12);
        float s = bdt
            + t0.x * wdt[0]  + t0.y * wdt[1]  + t0.z * wdt[2]  + t0.w * wdt[3]
            + t1.x * wdt[4]  + t1.y * wdt[5]  + t1.z * wdt[6]  + t1.w * wdt[7]
            + t2.x * wdt[8]  + t2.y * wdt[9]  + t2.z * wdt[10] + t2.w * wdt[11]
            + t3.x * wdt[12] + t3.y * wdt[13] + t3.z * wdt[14] + t3.w * wdt[15];
        float dtv = softplusf(s);
        float uv  = u[row * DIN + d];
        float du  = dtv * uv;
        float4 B0 = *(const float4*)(pr + DTR + nb);
        float4 B1 = *(const float4*)(pr + DTR + nb + 4);
        float Bn[8] = {B0.x, B0.y, B0.z, B0.w, B1.x, B1.y, B1.z, B1.w};
#pragma unroll
        for (int j = 0; j < 8; ++j) {
            float e = __expf(dtv * A[j]);
            h[j] = e * h[j] + du * Bn[j];
            p[j] *= e;
        }
    }

    size_t base = (((size_t)b * NC + c) * NST + nb) * DIN + d;
#pragma unroll
    for (int j = 0; j < 8; ++j) {
        P[base + (size_t)j * DIN] = p[j];
        F[base + (size_t)j * DIN] = h[j];
    }
}

// ---------------- scan phase B: prefix over chunks (prefetched) ----------------
__global__ __launch_bounds__(256) void scan_prefix(
    const float* __restrict__ P,
    const float* __restrict__ F,
    float* __restrict__ HST)
{
    int gid = blockIdx.x * 256 + threadIdx.x;
    int d = gid & (DIN - 1);
    int n = (gid >> 9) & (NST - 1);
    int b = gid >> 13;

    const size_t stride = (size_t)NST * DIN;
    size_t idx = (((size_t)b * NC + 0) * NST + n) * DIN + d;

    float pc = P[idx], fc = F[idx];
    float h = 0.f;
    for (int c = 0; c < NC; ++c) {
        float pn = 0.f, fn = 0.f;
        if (c + 1 < NC) {
            pn = P[idx + stride];
            fn = F[idx + stride];
        }
        HST[idx] = h;
        h = pc * h + fc;
        pc = pn; fc = fn;
        idx += stride;
    }
}

// ---------------- scan phase C: rescan + gate (dt fused, n split) ----------------
__global__ __launch_bounds__(256) void scan_rescan_gate(
    const float* __restrict__ u,      // also output g
    const float* __restrict__ proj,
    const float* __restrict__ dpw,
    const float* __restrict__ dpb,
    const float* __restrict__ Alog,
    const float* __restrict__ Dsk,
    const float* __restrict__ z,
    const float* __restrict__ HST,
    float* __restrict__ g)
{
    int gid = blockIdx.x * 256 + threadIdx.x;
    int ng = gid & 1;
    int d  = (gid >> 1) & (DIN - 1);
    int c  = (gid >> 10) & (NC - 1);
    int b  = gid >> 15;
    const int nb = ng * 8;

    float A[8];
#pragma unroll
    for (int j = 0; j < 8; ++j) A[j] = -__expf(Alog[d * NST + nb + j]);

    float wdt[16];
#pragma unroll
    for (int r4 = 0; r4 < 4; ++r4) {
        float4 v = *(const float4*)(dpw + d * DTR + r4 * 4);
        wdt[r4 * 4 + 0] = v.x; wdt[r4 * 4 + 1] = v.y;
        wdt[r4 * 4 + 2] = v.z; wdt[r4 * 4 + 3] = v.w;
    }
    const float bdt = dpb[d];
    const float Dv  = Dsk[d];

    float h[8];
    {
        size_t base = (((size_t)b * NC + c) * NST + nb) * DIN + d;
#pragma unroll
        for (int j = 0; j < 8; ++j) h[j] = HST[base + (size_t)j * DIN];
    }

    const int l0 = c * CL;
    for (int l = l0; l < l0 + CL; ++l) {
        size_t row = (size_t)b * Ll + l;
        const float* pr = proj + row * 48;
        float4 t0 = *(const float4*)(pr + 0);
        float4 t1 = *(const float4*)(pr + 4);
        float4 t2 = *(const float4*)(pr + 8);
        float4 t3 = *(const float4*)(pr + 12);
        float s = bdt
            + t0.x * wdt[0]  + t0.y * wdt[1]  + t0.z * wdt[2]  + t0.w * wdt[3]
            + t1.x * wdt[4]  + t1.y * wdt[5]  + t1.z * wdt[6]  + t1.w * wdt[7]
            + t2.x * wdt[8]  + t2.y * wdt[9]  + t2.z * wdt[10] + t2.w * wdt[11]
            + t3.x * wdt[12] + t3.y * wdt[13] + t3.z * wdt[14] + t3.w * wdt[15];
        float dtv = softplusf(s);
        float uv  = u[row * DIN + d];
        float du  = dtv * uv;
        float4 B0 = *(const float4*)(pr + DTR + nb);
        float4 B1 = *(const float4*)(pr + DTR + nb + 4);
        float4 C0 = *(const float4*)(pr + 2 * DTR + nb);
        float4 C1 = *(const float4*)(pr + 2 * DTR + nb + 4);
        float Bn[8] = {B0.x, B0.y, B0.z, B0.w, B1.x, B1.y, B1.z, B1.w};
        float Cn[8] = {C0.x, C0.y, C0.z, C0.w, C1.x, C1.y, C1.z, C1.w};
        float y = 0.f;
#pragma unroll
        for (int j = 0; j < 8; ++j) {
            float e = __expf(dtv * A[j]);
            h[j] = e * h[j] + du * Bn[j];
            y += h[j] * Cn[j];
        }
        y += __shfl_xor(y, 1);   // combine the two 8-state halves
        if (ng == 0) {
            float zv = z[row * DIN + d];
            float sig = zv / (1.f + __expf(-zv));
            g[row * DIN + d] = (y + Dv * uv) * sig;
        }
    }
}

// ---------------- head ----------------
__global__ void head_kernel(const float* __restrict__ h,
                            const float* __restrict__ hw,
                            const float* __restrict__ hb,
                            float* __restrict__ out)
{
    int b = blockIdx.x;
    int t = threadIdx.x;  // 64
    const float* row = h + ((size_t)b * Ll + (Ll - 1)) * Hh;
    float s = 0.f;
    for (int j = t; j < Hh; j += 64) s += row[j] * hw[j];
#pragma unroll
    for (int off = 32; off; off >>= 1) s += __shfl_down(s, off);
    if (t == 0) out[b] = s + hb[0];
}

extern "C" void kernel_launch(void* const* d_in, const int* in_sizes, int n_in,
                              void* d_out, int out_size, void* d_ws, size_t ws_size,
                              hipStream_t stream)
{
    const float* x    = (const float*)d_in[0];
    const float* pw   = (const float*)d_in[1];
    const float* pb   = (const float*)d_in[2];
    const float* ipw  = (const float*)d_in[3];
    const float* cw   = (const float*)d_in[4];
    const float* cb   = (const float*)d_in[5];
    const float* xpw  = (const float*)d_in[6];
    const float* dpw  = (const float*)d_in[7];
    const float* dpb  = (const float*)d_in[8];
    const float* Alog = (const float*)d_in[9];
    const float* Dsk  = (const float*)d_in[10];
    const float* opw  = (const float*)d_in[11];
    const float* hw   = (const float*)d_in[12];
    const float* hb   = (const float*)d_in[13];
    float* out = (float*)d_out;
    float* ws  = (float*)d_ws;

    float* h_buf[2] = { ws + OFF_H0, ws + OFF_H1 };
    float* xin  = ws + OFF_XIN;
    float* zb   = ws + OFF_Z;
    float* ub   = ws + OFF_U;
    float* prj  = ws + OFF_PROJ;
    float* hst  = ws + OFF_HST;
    unsigned short* wc = (unsigned short*)(ws + OFF_WC);

    const int M = Bb * Ll;  // 16384

    // ---- pre-convert weights to bf16 hi/lo ----
    convert_w_kernel<<<(Hh * OBS / 4 + 255) / 256, 256, 0, stream>>>(
        pw, wc + WPW_HI, wc + WPW_LO, Hh * OBS / 4);
    convert_w_kernel<<<(NBLK * 2 * DIN * Hh / 4 + 255) / 256, 256, 0, stream>>>(
        ipw, wc + WIPW_HI, wc + WIPW_LO, NBLK * 2 * DIN * Hh / 4);
    convert_w_kernel<<<(NBLK * Hh * DIN / 4 + 255) / 256, 256, 0, stream>>>(
        opw, wc + WOPW_HI, wc + WOPW_LO, NBLK * Hh * DIN / 4);

    // h = x @ proj_w^T + proj_b : M x 256, K=64 (MFMA)
    gemm_mfma3<64, 1><<<dim3(Hh / 128, M / 64), 256, 0, stream>>>(
        x, OBS, wc + WPW_HI, wc + WPW_LO, pb, h_buf[0], nullptr, Hh, OBS, Hh);

    int cur = 0;
    for (int i = 0; i < NBLK; ++i) {
        const unsigned short* ipwh = wc + WIPW_HI + (size_t)i * 2 * DIN * Hh;
        const unsigned short* ipwl = wc + WIPW_LO + (size_t)i * 2 * DIN * Hh;
        const unsigned short* opwh = wc + WOPW_HI + (size_t)i * Hh * DIN;
        const unsigned short* opwl = wc + WOPW_LO + (size_t)i * Hh * DIN;
        const float* cw_i  = cw  + (size_t)i * DIN * DCV;
        const float* cb_i  = cb  + (size_t)i * DIN;
        const float* xpw_i = xpw + (size_t)i * 48 * DIN;
        const float* dpw_i = dpw + (size_t)i * DIN * DTR;
        const float* dpb_i = dpb + (size_t)i * DIN;
        const float* Al_i  = Alog + (size_t)i * DIN * NST;
        const float* Dk_i  = Dsk + (size_t)i * DIN;

        // xz = h @ ipw^T -> split xin / z : N=1024, K=256 (MFMA)
        gemm_mfma3<128, 2><<<dim3(2 * DIN / 128, M / 128), 256, 0, stream>>>(
            h_buf[cur], Hh, ipwh, ipwl, nullptr, xin, zb, 2 * DIN, Hh, DIN);

        // u = silu(conv(xin) + cb)
        conv_silu_kernel<<<(M * DIN / 4) / 256, 256, 0, stream>>>(
            xin, cw_i, cb_i, ub, M * DIN / 4);

        // proj = u @ xpw^T : N=48 (fp32)
        gemm_nt<0><<<dim3(1, M / 64), 256, 0, stream>>>(
            ub, DIN, xpw_i, nullptr, prj, nullptr, M, 48, DIN, 48);

        // ---- chunked scan (dt computed on the fly from proj) ----
        float* Pbuf = h_buf[cur];
        float* Fbuf = h_buf[cur ^ 1];
        scan_chunk_reduce<<<(Bb * NC * DIN * 2) / 256, 256, 0, stream>>>(
            ub, prj, dpw_i, dpb_i, Al_i, Pbuf, Fbuf);
        scan_prefix<<<(Bb * NST * DIN) / 256, 256, 0, stream>>>(
            Pbuf, Fbuf, hst);
        scan_rescan_gate<<<(Bb * NC * DIN * 2) / 256, 256, 0, stream>>>(
            ub, prj, dpw_i, dpb_i, Al_i, Dk_i, zb, hst, ub);

        // h_next = g @ opw^T : N=256, K=512 (MFMA)
        gemm_mfma3<64, 1><<<dim3(Hh / 128, M / 64), 256, 0, stream>>>(
            ub, DIN, opwh, opwl, nullptr, h_buf[cur ^ 1], nullptr, Hh, DIN, Hh);

        cur ^= 1;
    }

    head_kernel<<<Bb, 64, 0, stream>>>(h_buf[cur], hw, hb, out);
}

// Round 5
// 889.642 us; speedup vs baseline: 1.6400x; 1.6400x over previous
//
#include <hip/hip_runtime.h>
#include <cstddef>

#define Bb 16
#define Ll 1024
#define OBS 64
#define Hh 256
#define NBLK 4
#define NST 16
#define DCV 4
#define DIN 512
#define DTR 16
#define NC 32            // chunks over L
#define CL (Ll / NC)     // 32 steps per chunk

typedef short short8 __attribute__((ext_vector_type(8)));
typedef float f32x4 __attribute__((ext_vector_type(4)));

// ---------------- workspace layout (floats) ----------------
static const size_t OFF_H0   = 0;
static const size_t OFF_H1   = OFF_H0 + (size_t)Bb * Ll * Hh;
static const size_t OFF_XIN  = OFF_H1 + (size_t)Bb * Ll * Hh;        // xin, later reused as dt
static const size_t OFF_Z    = OFF_XIN + (size_t)Bb * Ll * DIN;
static const size_t OFF_U    = OFF_Z   + (size_t)Bb * Ll * DIN;
static const size_t OFF_PROJ = OFF_U   + (size_t)Bb * Ll * DIN;      // [M,48]
static const size_t OFF_HST  = OFF_PROJ + (size_t)Bb * Ll * 48;      // [B,NC,NST,DIN]
static const size_t OFF_WC   = OFF_HST + (size_t)Bb * NC * NST * DIN;
// ushort offsets inside WC region:
static const size_t WPW_HI  = 0;
static const size_t WPW_LO  = 16384;
static const size_t WIPW_HI = 32768;
static const size_t WIPW_LO = WIPW_HI + 1048576;
static const size_t WOPW_HI = WIPW_LO + 1048576;
static const size_t WOPW_LO = WOPW_HI + 524288;

__device__ inline unsigned short f32_to_bf16(float v) {
    unsigned int u = __float_as_uint(v);
    u += 0x7fffu + ((u >> 16) & 1u);
    return (unsigned short)(u >> 16);
}
__device__ inline float bf16_to_f32(unsigned short h) {
    return __uint_as_float((unsigned int)h << 16);
}
__device__ inline float softplusf(float s) {
    return fmaxf(s, 0.f) + log1pf(__expf(-fabsf(s)));
}

// ---------------- weight fp32 -> bf16 hi/lo conversion ----------------
__global__ __launch_bounds__(256) void convert_w_kernel(
    const float* __restrict__ w,
    unsigned short* __restrict__ hi,
    unsigned short* __restrict__ lo, int n4)
{
    int i = blockIdx.x * 256 + threadIdx.x;
    if (i >= n4) return;
    float4 v4 = ((const float4*)w)[i];
    float vv[4] = {v4.x, v4.y, v4.z, v4.w};
#pragma unroll
    for (int e = 0; e < 4; ++e) {
        unsigned short hb = f32_to_bf16(vv[e]);
        float res = vv[e] - bf16_to_f32(hb);
        hi[i * 4 + e] = hb;
        lo[i * 4 + e] = f32_to_bf16(res);
    }
}

// ---------------- bf16x3 MFMA GEMM: C[M,N'] = A[M,K](fp32) * W[N,K]^T ----------------
template <int BM, int WR>
__global__ __launch_bounds__(256) void gemm_mfma3(
    const float* __restrict__ A, int lda,
    const unsigned short* __restrict__ Whi,
    const unsigned short* __restrict__ Wlo,
    const float* __restrict__ bias,
    float* __restrict__ C0,
    float* __restrict__ C1,
    int N, int K, int splitN)
{
    constexpr int WC_ = 4 / WR;
    constexpr int MI = (BM / WR) / 16;
    constexpr int NJ = (128 / WC_) / 16;
    constexpr int ASLOT = BM * 4 / 256;

    __shared__ unsigned short AsH[BM * 32], AsL[BM * 32];
    __shared__ unsigned short BsH[128 * 32], BsL[128 * 32];

    const int tid  = threadIdx.x;
    const int lane = tid & 63;
    const int w    = tid >> 6;
    const int wr   = w / WC_;
    const int wc   = w % WC_;
    const int m0   = blockIdx.y * BM;
    const int n0   = blockIdx.x * 128;

    f32x4 acc[MI][NJ] = {};

    for (int k0 = 0; k0 < K; k0 += 32) {
#pragma unroll
        for (int sI = 0; sI < ASLOT; ++sI) {
            int s = tid + sI * 256;
            int row = s >> 2, kb = s & 3;
            const float* ap = A + (size_t)(m0 + row) * lda + k0 + kb * 8;
            float4 v0 = *(const float4*)ap;
            float4 v1 = *(const float4*)(ap + 4);
            float vv[8] = {v0.x, v0.y, v0.z, v0.w, v1.x, v1.y, v1.z, v1.w};
            short8 h8, l8;
#pragma unroll
            for (int e = 0; e < 8; ++e) {
                unsigned short hb = f32_to_bf16(vv[e]);
                float res = vv[e] - bf16_to_f32(hb);
                h8[e] = (short)hb;
                l8[e] = (short)f32_to_bf16(res);
            }
            *(short8*)&AsH[s * 8] = h8;
            *(short8*)&AsL[s * 8] = l8;
        }
#pragma unroll
        for (int sI = 0; sI < 2; ++sI) {
            int s = tid + sI * 256;
            int row = s >> 2, kb = s & 3;
            size_t off = (size_t)(n0 + row) * K + k0 + kb * 8;
            *(short8*)&BsH[s * 8] = *(const short8*)(Whi + off);
            *(short8*)&BsL[s * 8] = *(const short8*)(Wlo + off);
        }
        __syncthreads();

        const int rr = lane & 15;
        const int kq = lane >> 4;
        short8 ah[MI], al[MI];
#pragma unroll
        for (int i = 0; i < MI; ++i) {
            int row = wr * (BM / WR) + i * 16 + rr;
            ah[i] = *(const short8*)&AsH[row * 32 + kq * 8];
            al[i] = *(const short8*)&AsL[row * 32 + kq * 8];
        }
#pragma unroll
        for (int j = 0; j < NJ; ++j) {
            int col = wc * (128 / WC_) + j * 16 + rr;
            short8 bh = *(const short8*)&BsH[col * 32 + kq * 8];
            short8 bl = *(const short8*)&BsL[col * 32 + kq * 8];
#pragma unroll
            for (int i = 0; i < MI; ++i) {
                acc[i][j] = __builtin_amdgcn_mfma_f32_16x16x32_bf16(ah[i], bh, acc[i][j], 0, 0, 0);
                acc[i][j] = __builtin_amdgcn_mfma_f32_16x16x32_bf16(ah[i], bl, acc[i][j], 0, 0, 0);
                acc[i][j] = __builtin_amdgcn_mfma_f32_16x16x32_bf16(al[i], bh, acc[i][j], 0, 0, 0);
            }
        }
        __syncthreads();
    }

    const int rr = lane & 15;
    const int rq = lane >> 4;
#pragma unroll
    for (int i = 0; i < MI; ++i) {
#pragma unroll
        for (int j = 0; j < NJ; ++j) {
            int col = n0 + wc * (128 / WC_) + j * 16 + rr;
            float badd = bias ? bias[col] : 0.f;
#pragma unroll
            for (int r = 0; r < 4; ++r) {
                int row = m0 + wr * (BM / WR) + i * 16 + rq * 4 + r;
                float v = acc[i][j][r] + badd;
                if (col < splitN)
                    C0[(size_t)row * splitN + col] = v;
                else
                    C1[(size_t)row * (N - splitN) + (col - splitN)] = v;
            }
        }
    }
}

// ---------------- fp32 GEMM (x_proj N=48, dt N=512 K=16) ----------------
template <int ACT>
__global__ __launch_bounds__(256) void gemm_nt(
    const float* __restrict__ A, int lda,
    const float* __restrict__ W,
    const float* __restrict__ bias,
    float* __restrict__ C0, float* __restrict__ C1,
    int M, int N, int K, int splitN)
{
    __shared__ float As[16][68];
    __shared__ float Ws[16][68];

    const int tid = threadIdx.x;
    const int m0 = blockIdx.y * 64;
    const int n0 = blockIdx.x * 64;
    const int tx = tid & 15;
    const int ty = tid >> 4;
    const int r  = tid >> 2;
    const int kv = (tid & 3) * 4;

    float acc[4][4] = {};

    for (int k0 = 0; k0 < K; k0 += 16) {
        float4 a4;
        {
            const float* ap = A + (size_t)(m0 + r) * lda + (k0 + kv);
            a4 = *(const float4*)ap;
        }
        float4 w4 = make_float4(0.f, 0.f, 0.f, 0.f);
        if (n0 + r < N) {
            const float* wp = W + (size_t)(n0 + r) * K + (k0 + kv);
            w4 = *(const float4*)wp;
        }
        __syncthreads();
        As[kv + 0][r] = a4.x; As[kv + 1][r] = a4.y;
        As[kv + 2][r] = a4.z; As[kv + 3][r] = a4.w;
        Ws[kv + 0][r] = w4.x; Ws[kv + 1][r] = w4.y;
        Ws[kv + 2][r] = w4.z; Ws[kv + 3][r] = w4.w;
        __syncthreads();
#pragma unroll
        for (int kk = 0; kk < 16; ++kk) {
            float4 av = *(const float4*)&As[kk][ty * 4];
            float4 wv = *(const float4*)&Ws[kk][tx * 4];
            float am[4] = {av.x, av.y, av.z, av.w};
            float wn[4] = {wv.x, wv.y, wv.z, wv.w};
#pragma unroll
            for (int i = 0; i < 4; ++i)
#pragma unroll
                for (int j = 0; j < 4; ++j)
                    acc[i][j] += am[i] * wn[j];
        }
    }

#pragma unroll
    for (int i = 0; i < 4; ++i) {
        const int row = m0 + ty * 4 + i;
#pragma unroll
        for (int j = 0; j < 4; ++j) {
            const int col = n0 + tx * 4 + j;
            if (col >= N) continue;
            float v = acc[i][j];
            if (bias) v += bias[col];
            if (ACT == 1) v = softplusf(v);
            if (col < splitN)
                C0[(size_t)row * splitN + col] = v;
            else
                C1[(size_t)row * (N - splitN) + (col - splitN)] = v;
        }
    }
}

// ---------------- causal depthwise conv1d + silu (float4 over d) ----------------
__global__ __launch_bounds__(256) void conv_silu_kernel(
    const float* __restrict__ xin,
    const float* __restrict__ cw,
    const float* __restrict__ cb,
    float* __restrict__ u, int total4)
{
    int i = blockIdx.x * 256 + threadIdx.x;
    if (i >= total4) return;
    int d4 = (i & (DIN / 4 - 1)) * 4;
    int bl = i >> 7;
    int l  = bl & (Ll - 1);

    float4 cb4 = *(const float4*)(cb + d4);
    float acc[4] = {cb4.x, cb4.y, cb4.z, cb4.w};
    float4 cw0 = *(const float4*)(cw + (d4 + 0) * 4);
    float4 cw1 = *(const float4*)(cw + (d4 + 1) * 4);
    float4 cw2 = *(const float4*)(cw + (d4 + 2) * 4);
    float4 cw3 = *(const float4*)(cw + (d4 + 3) * 4);
    const float* cwp[4] = {(const float*)&cw0, (const float*)&cw1,
                           (const float*)&cw2, (const float*)&cw3};
#pragma unroll
    for (int k = 0; k < DCV; ++k) {
        int ls = l - (DCV - 1) + k;
        if (ls >= 0) {
            float4 xv = *(const float4*)(xin + (size_t)(bl - (DCV - 1) + k) * DIN + d4);
            float xj[4] = {xv.x, xv.y, xv.z, xv.w};
#pragma unroll
            for (int j = 0; j < 4; ++j) acc[j] += xj[j] * cwp[j][k];
        }
    }
    float4 o;
    o.x = acc[0] / (1.f + __expf(-acc[0]));
    o.y = acc[1] / (1.f + __expf(-acc[1]));
    o.z = acc[2] / (1.f + __expf(-acc[2]));
    o.w = acc[3] / (1.f + __expf(-acc[3]));
    *(float4*)(u + (size_t)bl * DIN + d4) = o;
}

// ---------------- scan phase A: chunk-local reduce ----------------
// Half-wave n-split: lanes 0..31 -> states 0..7, lanes 32..63 -> states 8..15,
// both halves cover the same 32 consecutive d's. dt read from buffer.
__global__ __launch_bounds__(256) void scan_chunk_reduce(
    const float* __restrict__ dt,     // [B*L, DIN]
    const float* __restrict__ u,      // [B*L, DIN]
    const float* __restrict__ proj,   // [B*L, 48]
    const float* __restrict__ Alog,   // [DIN, NST]
    float* __restrict__ P,            // [B, NC, NST, DIN]
    float* __restrict__ F)
{
    const int tid  = threadIdx.x;
    const int lane = tid & 63;
    const int widx = blockIdx.x * 4 + (tid >> 6);
    const int ng = lane >> 5;          // 0 or 1
    const int dd = lane & 31;
    const int d32 = widx & 15;         // DIN/32 = 16
    const int c   = (widx >> 4) & (NC - 1);
    const int b   = widx >> 9;
    const int d   = d32 * 32 + dd;
    const int nb  = ng * 8;

    float A[8];
#pragma unroll
    for (int j = 0; j < 8; ++j) A[j] = -__expf(Alog[d * NST + nb + j]);

    float h[8], p[8];
#pragma unroll
    for (int j = 0; j < 8; ++j) { h[j] = 0.f; p[j] = 1.f; }

    const int l0 = c * CL;
    for (int l = l0; l < l0 + CL; ++l) {
        size_t row = (size_t)b * Ll + l;
        float dtv = dt[row * DIN + d];
        float uv  = u[row * DIN + d];
        float du  = dtv * uv;
        const float* pr = proj + row * 48;
        float4 B0 = *(const float4*)(pr + DTR + nb);
        float4 B1 = *(const float4*)(pr + DTR + nb + 4);
        float Bn[8] = {B0.x, B0.y, B0.z, B0.w, B1.x, B1.y, B1.z, B1.w};
#pragma unroll
        for (int j = 0; j < 8; ++j) {
            float e = __expf(dtv * A[j]);
            h[j] = e * h[j] + du * Bn[j];
            p[j] *= e;
        }
    }

    size_t base = (((size_t)b * NC + c) * NST + nb) * DIN + d;
#pragma unroll
    for (int j = 0; j < 8; ++j) {
        P[base + (size_t)j * DIN] = p[j];
        F[base + (size_t)j * DIN] = h[j];
    }
}

// ---------------- scan phase B: prefix over chunks (prefetched) ----------------
__global__ __launch_bounds__(256) void scan_prefix(
    const float* __restrict__ P,
    const float* __restrict__ F,
    float* __restrict__ HST)
{
    int gid = blockIdx.x * 256 + threadIdx.x;
    int d = gid & (DIN - 1);
    int n = (gid >> 9) & (NST - 1);
    int b = gid >> 13;

    const size_t stride = (size_t)NST * DIN;
    size_t idx = (((size_t)b * NC + 0) * NST + n) * DIN + d;

    float pc = P[idx], fc = F[idx];
    float h = 0.f;
    for (int c = 0; c < NC; ++c) {
        float pn = 0.f, fn = 0.f;
        if (c + 1 < NC) {
            pn = P[idx + stride];
            fn = F[idx + stride];
        }
        HST[idx] = h;
        h = pc * h + fc;
        pc = pn; fc = fn;
        idx += stride;
    }
}

// ---------------- scan phase C: rescan + gate (half-wave n-split) ----------------
__global__ __launch_bounds__(256) void scan_rescan_gate(
    const float* __restrict__ dt,
    const float* __restrict__ u,      // also output g
    const float* __restrict__ proj,
    const float* __restrict__ Alog,
    const float* __restrict__ Dsk,
    const float* __restrict__ z,
    const float* __restrict__ HST,
    float* __restrict__ g)
{
    const int tid  = threadIdx.x;
    const int lane = tid & 63;
    const int widx = blockIdx.x * 4 + (tid >> 6);
    const int ng = lane >> 5;
    const int dd = lane & 31;
    const int d32 = widx & 15;
    const int c   = (widx >> 4) & (NC - 1);
    const int b   = widx >> 9;
    const int d   = d32 * 32 + dd;
    const int nb  = ng * 8;

    float A[8];
#pragma unroll
    for (int j = 0; j < 8; ++j) A[j] = -__expf(Alog[d * NST + nb + j]);
    const float Dv = Dsk[d];

    float h[8];
    {
        size_t base = (((size_t)b * NC + c) * NST + nb) * DIN + d;
#pragma unroll
        for (int j = 0; j < 8; ++j) h[j] = HST[base + (size_t)j * DIN];
    }

    const int l0 = c * CL;
    for (int l = l0; l < l0 + CL; ++l) {
        size_t row = (size_t)b * Ll + l;
        float dtv = dt[row * DIN + d];
        float uv  = u[row * DIN + d];
        float du  = dtv * uv;
        const float* pr = proj + row * 48;
        float4 B0 = *(const float4*)(pr + DTR + nb);
        float4 B1 = *(const float4*)(pr + DTR + nb + 4);
        float4 C0 = *(const float4*)(pr + 2 * DTR + nb);
        float4 C1 = *(const float4*)(pr + 2 * DTR + nb + 4);
        float Bn[8] = {B0.x, B0.y, B0.z, B0.w, B1.x, B1.y, B1.z, B1.w};
        float Cn[8] = {C0.x, C0.y, C0.z, C0.w, C1.x, C1.y, C1.z, C1.w};
        float y = 0.f;
#pragma unroll
        for (int j = 0; j < 8; ++j) {
            float e = __expf(dtv * A[j]);
            h[j] = e * h[j] + du * Bn[j];
            y += h[j] * Cn[j];
        }
        y += __shfl_xor(y, 32);   // combine the two half-wave state groups
        if (ng == 0) {
            float zv = z[row * DIN + d];
            float sig = zv / (1.f + __expf(-zv));
            g[row * DIN + d] = (y + Dv * uv) * sig;
        }
    }
}

// ---------------- head ----------------
__global__ void head_kernel(const float* __restrict__ h,
                            const float* __restrict__ hw,
                            const float* __restrict__ hb,
                            float* __restrict__ out)
{
    int b = blockIdx.x;
    int t = threadIdx.x;  // 64
    const float* row = h + ((size_t)b * Ll + (Ll - 1)) * Hh;
    float s = 0.f;
    for (int j = t; j < Hh; j += 64) s += row[j] * hw[j];
#pragma unroll
    for (int off = 32; off; off >>= 1) s += __shfl_down(s, off);
    if (t == 0) out[b] = s + hb[0];
}

extern "C" void kernel_launch(void* const* d_in, const int* in_sizes, int n_in,
                              void* d_out, int out_size, void* d_ws, size_t ws_size,
                              hipStream_t stream)
{
    const float* x    = (const float*)d_in[0];
    const float* pw   = (const float*)d_in[1];
    const float* pb   = (const float*)d_in[2];
    const float* ipw  = (const float*)d_in[3];
    const float* cw   = (const float*)d_in[4];
    const float* cb   = (const float*)d_in[5];
    const float* xpw  = (const float*)d_in[6];
    const float* dpw  = (const float*)d_in[7];
    const float* dpb  = (const float*)d_in[8];
    const float* Alog = (const float*)d_in[9];
    const float* Dsk  = (const float*)d_in[10];
    const float* opw  = (const float*)d_in[11];
    const float* hw   = (const float*)d_in[12];
    const float* hb   = (const float*)d_in[13];
    float* out = (float*)d_out;
    float* ws  = (float*)d_ws;

    float* h_buf[2] = { ws + OFF_H0, ws + OFF_H1 };
    float* xin  = ws + OFF_XIN;
    float* zb   = ws + OFF_Z;
    float* ub   = ws + OFF_U;
    float* prj  = ws + OFF_PROJ;
    float* hst  = ws + OFF_HST;
    float* dtb  = xin;  // reuse xin region after conv
    unsigned short* wc = (unsigned short*)(ws + OFF_WC);

    const int M = Bb * Ll;  // 16384

    // ---- pre-convert weights to bf16 hi/lo ----
    convert_w_kernel<<<(Hh * OBS / 4 + 255) / 256, 256, 0, stream>>>(
        pw, wc + WPW_HI, wc + WPW_LO, Hh * OBS / 4);
    convert_w_kernel<<<(NBLK * 2 * DIN * Hh / 4 + 255) / 256, 256, 0, stream>>>(
        ipw, wc + WIPW_HI, wc + WIPW_LO, NBLK * 2 * DIN * Hh / 4);
    convert_w_kernel<<<(NBLK * Hh * DIN / 4 + 255) / 256, 256, 0, stream>>>(
        opw, wc + WOPW_HI, wc + WOPW_LO, NBLK * Hh * DIN / 4);

    // h = x @ proj_w^T + proj_b : M x 256, K=64 (MFMA)
    gemm_mfma3<64, 1><<<dim3(Hh / 128, M / 64), 256, 0, stream>>>(
        x, OBS, wc + WPW_HI, wc + WPW_LO, pb, h_buf[0], nullptr, Hh, OBS, Hh);

    int cur = 0;
    for (int i = 0; i < NBLK; ++i) {
        const unsigned short* ipwh = wc + WIPW_HI + (size_t)i * 2 * DIN * Hh;
        const unsigned short* ipwl = wc + WIPW_LO + (size_t)i * 2 * DIN * Hh;
        const unsigned short* opwh = wc + WOPW_HI + (size_t)i * Hh * DIN;
        const unsigned short* opwl = wc + WOPW_LO + (size_t)i * Hh * DIN;
        const float* cw_i  = cw  + (size_t)i * DIN * DCV;
        const float* cb_i  = cb  + (size_t)i * DIN;
        const float* xpw_i = xpw + (size_t)i * 48 * DIN;
        const float* dpw_i = dpw + (size_t)i * DIN * DTR;
        const float* dpb_i = dpb + (size_t)i * DIN;
        const float* Al_i  = Alog + (size_t)i * DIN * NST;
        const float* Dk_i  = Dsk + (size_t)i * DIN;

        // xz = h @ ipw^T -> split xin / z : N=1024, K=256 (MFMA)
        gemm_mfma3<128, 2><<<dim3(2 * DIN / 128, M / 128), 256, 0, stream>>>(
            h_buf[cur], Hh, ipwh, ipwl, nullptr, xin, zb, 2 * DIN, Hh, DIN);

        // u = silu(conv(xin) + cb)
        conv_silu_kernel<<<(M * DIN / 4) / 256, 256, 0, stream>>>(
            xin, cw_i, cb_i, ub, M * DIN / 4);

        // proj = u @ xpw^T : N=48 (fp32)
        gemm_nt<0><<<dim3(1, M / 64), 256, 0, stream>>>(
            ub, DIN, xpw_i, nullptr, prj, nullptr, M, 48, DIN, 48);

        // dt = softplus(dtl @ dpw^T + dpb) : N=512, K=16 (fp32), overwrites xin
        gemm_nt<1><<<dim3(DIN / 64, M / 64), 256, 0, stream>>>(
            prj, 48, dpw_i, dpb_i, dtb, nullptr, M, DIN, DTR, DIN);

        // ---- chunked scan ----
        float* Pbuf = h_buf[cur];
        float* Fbuf = h_buf[cur ^ 1];
        scan_chunk_reduce<<<(Bb * NC * DIN * 2) / 1024 * 4 / 4, 256, 0, stream>>>(
            dtb, ub, prj, Al_i, Pbuf, Fbuf);
        scan_prefix<<<(Bb * NST * DIN) / 256, 256, 0, stream>>>(
            Pbuf, Fbuf, hst);
        scan_rescan_gate<<<(Bb * NC * DIN * 2) / 1024 * 4 / 4, 256, 0, stream>>>(
            dtb, ub, prj, Al_i, Dk_i, zb, hst, ub);

        // h_next = g @ opw^T : N=256, K=512 (MFMA)
        gemm_mfma3<64, 1><<<dim3(Hh / 128, M / 64), 256, 0, stream>>>(
            ub, DIN, opwh, opwl, nullptr, h_buf[cur ^ 1], nullptr, Hh, DIN, Hh);

        cur ^= 1;
    }

    head_kernel<<<Bb, 64, 0, stream>>>(h_buf[cur], hw, hb, out);
}